// Round 7
// baseline (11995.470 us; speedup 1.0000x reference)
//
#include <hip/hip_runtime.h>
#include <math.h>
#include <limits.h>

typedef long long ll;

#define MAXCHAIN 4096
#define MAXP 49152
#define MAXOPS 49152
#define MAXR 64
#define PART_OFF 4096
#define CHAINS_OFF 16384
#define PEAKS_OFF (CHAINS_OFF + 128 * MAXCHAIN * 4)
#define OPS_OFF (PEAKS_OFF + MAXP * 4)
#define F0_OFF (OPS_OFF + (size_t)MAXOPS * 16)

static __device__ const double TWOPI = 6.283185307179586;

struct Ctrl {
  double gpeak, max_w, ps64;
  long long k_rem, tail;
  float mean32, median_raw, md32, minv_scaled32;
  unsigned amax_bits, minf0_bits, prefix;
  int cnt_pos, shift, n_starts, n_ends, nregions, n_peaks, n_ops, slab;
  int hist[256];
  int region_start[MAXR], region_end[MAXR];
  int chain_cnt[128];
  int chain_off[129];
  int region_ops[MAXR];
};

// ---------- exact-arith helpers (no FMA contraction) ----------
__device__ __forceinline__ double dmul(double a, double b) { return __dmul_rn(a, b); }
__device__ __forceinline__ double dadd(double a, double b) { return __dadd_rn(a, b); }
__device__ __forceinline__ double dsub(double a, double b) { return __dadd_rn(a, -b); }
__device__ __forceinline__ float fmul(float a, float b) { return __fmul_rn(a, b); }
__device__ __forceinline__ float fadd(float a, float b) { return __fadd_rn(a, b); }
__device__ __forceinline__ float fsub(float a, float b) { return __fadd_rn(a, -b); }

__device__ __forceinline__ float xval(const float* snd, float mean, ll t) {
  return fsub(snd[t], mean);
}

// Markstein correctly-rounded division: r = RN(1/d) precomputed.
__device__ __forceinline__ float div_exact(float x, float d, float r) {
  float q = __fmul_rn(x, r);
  float e = __fmaf_rn(-d, q, x);
  return __fmaf_rn(e, r, q);
}

// f0 = linear interp of pitch, computed exactly as numpy (f64 ops, one f32 round)
__device__ float f0_at(const float* pitch, ll t, ll S, double ratio) {
  double pos = dsub(dmul(dadd((double)t, 0.5), ratio), 0.5);
  double hi = (double)(S - 1);
  pos = fmin(fmax(pos, 0.0), hi);
  double fl = floor(pos);
  ll lo = (ll)fl;
  if (lo < 0) lo = 0;
  if (lo > S - 1) lo = S - 1;
  ll hii = lo + 1; if (hii > S - 1) hii = S - 1;
  double frac = dsub(pos, fl);
  double om = dsub(1.0, frac);
  double v = dadd(dmul((double)pitch[lo], om), dmul((double)pitch[hii], frac));
  return (float)v;
}

// frame index used by f0 interp at time t
__device__ __forceinline__ ll frame_lo(ll t, ll S, double ratio) {
  double pos = dsub(dmul(dadd((double)t, 0.5), ratio), 0.5);
  pos = fmin(fmax(pos, 0.0), (double)(S - 1));
  ll lo = (ll)floor(pos);
  if (lo < 0) lo = 0;
  if (lo > S - 1) lo = S - 1;
  return lo;
}

// identical arithmetic to f0_at; pitch values served from LDS slab [p0..p1]
__device__ __forceinline__ float f0_lds(const float* __restrict__ lpitch, int p0, int p1,
                                        const float* __restrict__ pitch,
                                        ll t, ll S, double ratio) {
  double pos = dsub(dmul(dadd((double)t, 0.5), ratio), 0.5);
  pos = fmin(fmax(pos, 0.0), (double)(S - 1));
  double fl = floor(pos);
  ll lo = (ll)fl;
  if (lo < 0) lo = 0;
  if (lo > S - 1) lo = S - 1;
  ll hii = lo + 1; if (hii > S - 1) hii = S - 1;
  double frac = dsub(pos, fl);
  double om = dsub(1.0, frac);
  float plo = (lo >= p0 && lo <= p1) ? lpitch[(int)(lo - p0)] : pitch[lo];
  float phi = (hii >= p0 && hii <= p1) ? lpitch[(int)(hii - p0)] : pitch[hii];
  return (float)dadd(dmul((double)plo, om), dmul((double)phi, frac));
}

// ---- fused pairwise sum-of-squares: template(A) + cand0(B) + optional cand1(C).
// Per-range accumulator chains identical to numpy's 8-accumulator pairwise
// scheme (streams independent; max-reduce order-insensitive) -> bit-identical.
template<bool HAS1>
__device__ void pw3_blk(const float* __restrict__ buf, int bA, int bB, int bC, int n,
                        float& outA, float& outB, float& outC, float& pkB, float& pkC) {
  if (n < 8) {
    float ra = 0.f;
    for (int i = 0; i < n; ++i) { float x = buf[bA + i]; ra = fadd(ra, fmul(x, x)); }
    float rb = 0.f;
    for (int i = 0; i < n; ++i) {
      float x = buf[bB + i]; pkB = fmaxf(pkB, fabsf(x)); rb = fadd(rb, fmul(x, x));
    }
    outA = ra; outB = rb;
    if (HAS1) {
      float rc = 0.f;
      for (int i = 0; i < n; ++i) {
        float x = buf[bC + i]; pkC = fmaxf(pkC, fabsf(x)); rc = fadd(rc, fmul(x, x));
      }
      outC = rc;
    }
    return;
  }
  float ca[8], cb[8], cc[8], na[8], nb[8], nc[8], rA[8], rB[8], rC[8];
  #pragma unroll
  for (int j = 0; j < 8; ++j) ca[j] = buf[bA + j];
  #pragma unroll
  for (int j = 0; j < 8; ++j) cb[j] = buf[bB + j];
  if (HAS1) {
    #pragma unroll
    for (int j = 0; j < 8; ++j) cc[j] = buf[bC + j];
  }
  int lim = n - (n & 7);
  bool hn = (8 < lim);
  if (hn) {
    #pragma unroll
    for (int j = 0; j < 8; ++j) na[j] = buf[bA + 8 + j];
    #pragma unroll
    for (int j = 0; j < 8; ++j) nb[j] = buf[bB + 8 + j];
    if (HAS1) {
      #pragma unroll
      for (int j = 0; j < 8; ++j) nc[j] = buf[bC + 8 + j];
    }
  }
  #pragma unroll
  for (int j = 0; j < 8; ++j) {
    pkB = fmaxf(pkB, fabsf(cb[j]));
    rA[j] = fmul(ca[j], ca[j]);
    rB[j] = fmul(cb[j], cb[j]);
    if (HAS1) { pkC = fmaxf(pkC, fabsf(cc[j])); rC[j] = fmul(cc[j], cc[j]); }
  }
  for (int i = 8; i < lim; i += 8) {
    #pragma unroll
    for (int j = 0; j < 8; ++j) { ca[j] = na[j]; cb[j] = nb[j]; if (HAS1) cc[j] = nc[j]; }
    bool hn2 = (i + 8 < lim);
    if (hn2) {
      #pragma unroll
      for (int j = 0; j < 8; ++j) na[j] = buf[bA + i + 8 + j];
      #pragma unroll
      for (int j = 0; j < 8; ++j) nb[j] = buf[bB + i + 8 + j];
      if (HAS1) {
        #pragma unroll
        for (int j = 0; j < 8; ++j) nc[j] = buf[bC + i + 8 + j];
      }
    }
    #pragma unroll
    for (int j = 0; j < 8; ++j) {
      pkB = fmaxf(pkB, fabsf(cb[j]));
      rA[j] = fadd(rA[j], fmul(ca[j], ca[j]));
      rB[j] = fadd(rB[j], fmul(cb[j], cb[j]));
      if (HAS1) {
        pkC = fmaxf(pkC, fabsf(cc[j]));
        rC[j] = fadd(rC[j], fmul(cc[j], cc[j]));
      }
    }
  }
  float resA = fadd(fadd(fadd(rA[0], rA[1]), fadd(rA[2], rA[3])),
                    fadd(fadd(rA[4], rA[5]), fadd(rA[6], rA[7])));
  float resB = fadd(fadd(fadd(rB[0], rB[1]), fadd(rB[2], rB[3])),
                    fadd(fadd(rB[4], rB[5]), fadd(rB[6], rB[7])));
  float resC = 0.f;
  if (HAS1)
    resC = fadd(fadd(fadd(rC[0], rC[1]), fadd(rC[2], rC[3])),
                fadd(fadd(rC[4], rC[5]), fadd(rC[6], rC[7])));
  for (int i = lim; i < n; ++i) {
    float xa = buf[bA + i];
    resA = fadd(resA, fmul(xa, xa));
    float xb = buf[bB + i];
    pkB = fmaxf(pkB, fabsf(xb));
    resB = fadd(resB, fmul(xb, xb));
    if (HAS1) {
      float xc = buf[bC + i];
      pkC = fmaxf(pkC, fabsf(xc));
      resC = fadd(resC, fmul(xc, xc));
    }
  }
  outA = resA; outB = resB;
  if (HAS1) outC = resC;
}

template<bool HAS1>
__device__ void pw3_sq(const float* __restrict__ buf, int bA, int bB, int bC, int n,
                       float& oA, float& oB, float& oC, float& pkB, float& pkC) {
  if (n <= 128) { pw3_blk<HAS1>(buf, bA, bB, bC, n, oA, oB, oC, pkB, pkC); return; }
  int n2 = (n >> 1); n2 -= (n2 & 7);
  float a1, b1v, c1v = 0.f;
  pw3_blk<HAS1>(buf, bA, bB, bC, n2, a1, b1v, c1v, pkB, pkC);
  int m = n - n2;
  if (m <= 128) {
    float a2, b2, c2 = 0.f;
    pw3_blk<HAS1>(buf, bA + n2, bB + n2, bC + n2, m, a2, b2, c2, pkB, pkC);
    oA = fadd(a1, a2); oB = fadd(b1v, b2);
    if (HAS1) oC = fadd(c1v, c2);
  } else {
    int m2 = (m >> 1); m2 -= (m2 & 7);
    float a2a, b2a, c2a = 0.f, a2b, b2b, c2b = 0.f;
    pw3_blk<HAS1>(buf, bA + n2, bB + n2, bC + n2, m2, a2a, b2a, c2a, pkB, pkC);
    pw3_blk<HAS1>(buf, bA + n2 + m2, bB + n2 + m2, bC + n2 + m2, m - m2, a2b, b2b, c2b, pkB, pkC);
    oA = fadd(a1, fadd(a2a, a2b)); oB = fadd(b1v, fadd(b2a, b2b));
    if (HAS1) oC = fadd(c1v, fadd(c2a, c2b));
  }
}

// Fused dual-slot BLAS-sgemv mimic over LDS; tm via aligned float4 reads.
// Per-slot accumulator order identical to the passing version -> bit-identical.
template<bool HAS1>
__device__ void dot2_lds(const float* __restrict__ buf, int b0, int b1,
                         float d0, float r0, float d1, float r1,
                         const float* __restrict__ tm, int w,
                         float& out0, float& out1) {
  float a0[8], a1a[8];
  #pragma unroll
  for (int j = 0; j < 8; ++j) { a0[j] = 0.f; a1a[j] = 0.f; }
  int lim = w - (w & 7);
  if (lim > 0) {
    float cs0[8], cs1[8], ct[8], ns0[8], ns1[8], nt[8];
    #pragma unroll
    for (int j = 0; j < 8; ++j) cs0[j] = buf[b0 + j];
    if (HAS1) {
      #pragma unroll
      for (int j = 0; j < 8; ++j) cs1[j] = buf[b1 + j];
    }
    {
      float4 t4a = *reinterpret_cast<const float4*>(tm);
      float4 t4b = *reinterpret_cast<const float4*>(tm + 4);
      ct[0] = t4a.x; ct[1] = t4a.y; ct[2] = t4a.z; ct[3] = t4a.w;
      ct[4] = t4b.x; ct[5] = t4b.y; ct[6] = t4b.z; ct[7] = t4b.w;
    }
    for (int k = 0; k < lim; k += 8) {
      bool hn = (k + 8 < lim);
      if (hn) {
        #pragma unroll
        for (int j = 0; j < 8; ++j) ns0[j] = buf[b0 + k + 8 + j];
        if (HAS1) {
          #pragma unroll
          for (int j = 0; j < 8; ++j) ns1[j] = buf[b1 + k + 8 + j];
        }
        float4 t4a = *reinterpret_cast<const float4*>(tm + k + 8);
        float4 t4b = *reinterpret_cast<const float4*>(tm + k + 12);
        nt[0] = t4a.x; nt[1] = t4a.y; nt[2] = t4a.z; nt[3] = t4a.w;
        nt[4] = t4b.x; nt[5] = t4b.y; nt[6] = t4b.z; nt[7] = t4b.w;
      }
      #pragma unroll
      for (int j = 0; j < 8; ++j) {
        a0[j] = __fmaf_rn(div_exact(cs0[j], d0, r0), ct[j], a0[j]);
        if (HAS1) a1a[j] = __fmaf_rn(div_exact(cs1[j], d1, r1), ct[j], a1a[j]);
      }
      if (hn) {
        #pragma unroll
        for (int j = 0; j < 8; ++j) { cs0[j] = ns0[j]; if (HAS1) cs1[j] = ns1[j]; ct[j] = nt[j]; }
      }
    }
  }
  #pragma unroll
  for (int j = 0; j < 7; ++j)
    if (lim + j < w) {
      float tv = tm[lim + j];
      a0[j] = __fmaf_rn(div_exact(buf[b0 + lim + j], d0, r0), tv, a0[j]);
      if (HAS1) a1a[j] = __fmaf_rn(div_exact(buf[b1 + lim + j], d1, r1), tv, a1a[j]);
    }
  out0 = fadd(fadd(fadd(a0[0], a0[1]), fadd(a0[2], a0[3])),
              fadd(fadd(a0[4], a0[5]), fadd(a0[6], a0[7])));
  if (HAS1)
    out1 = fadd(fadd(fadd(a1a[0], a1a[1]), fadd(a1a[2], a1a[3])),
                fadd(fadd(a1a[4], a1a[5]), fadd(a1a[6], a1a[7])));
  else out1 = -INFINITY;
}

// ---------- kernels ----------
__global__ void k_init(char* wsb) {
  Ctrl* c = (Ctrl*)wsb;
  int t = threadIdx.x;
  for (int b = t; b < 256; b += blockDim.x) c->hist[b] = 0;
  for (int b = t; b < 128; b += blockDim.x) c->chain_cnt[b] = 0;
  for (int b = t; b < MAXR; b += blockDim.x) c->region_ops[b] = 0;
  if (t == 0) {
    c->amax_bits = 0u; c->minf0_bits = 0xFFFFFFFFu;
    c->cnt_pos = 0; c->n_starts = 0; c->n_ends = 0; c->n_ops = 0;
    c->nregions = 0; c->n_peaks = 0; c->tail = 0; c->slab = MAXOPS;
  }
}

__global__ void k_sum_partial(const float* __restrict__ snd, ll T, char* wsb) {
  __shared__ double sd[256];
  double local = 0.0;
  ll stride = (ll)gridDim.x * blockDim.x;
  for (ll t = (ll)blockIdx.x * blockDim.x + threadIdx.x; t < T; t += stride)
    local += (double)snd[t];
  sd[threadIdx.x] = local; __syncthreads();
  for (int o = 128; o > 0; o >>= 1) {
    if ((int)threadIdx.x < o) sd[threadIdx.x] += sd[threadIdx.x + o];
    __syncthreads();
  }
  if (threadIdx.x == 0) ((double*)(wsb + PART_OFF))[blockIdx.x] = sd[0];
}

__global__ void k_sum_final(char* wsb, ll T, int nparts) {
  __shared__ double sd[256];
  double local = 0.0;
  const double* p = (const double*)(wsb + PART_OFF);
  for (int i = threadIdx.x; i < nparts; i += blockDim.x) local += p[i];
  sd[threadIdx.x] = local; __syncthreads();
  for (int o = 128; o > 0; o >>= 1) {
    if ((int)threadIdx.x < o) sd[threadIdx.x] += sd[threadIdx.x + o];
    __syncthreads();
  }
  if (threadIdx.x == 0) ((Ctrl*)wsb)->mean32 = (float)(sd[0] / (double)T);
}

// cache exact f32 bits of f0 over all T (used by scan/hist bulk passes)
__global__ void k_f0(const float* __restrict__ pitch, ll T, ll S, double ratio,
                     unsigned* __restrict__ bits) {
  ll stride = (ll)gridDim.x * blockDim.x;
  for (ll t = (ll)blockIdx.x * blockDim.x + threadIdx.x; t < T; t += stride)
    bits[t] = __float_as_uint(f0_at(pitch, t, S, ratio));
}

__global__ void k_scan(const float* __restrict__ snd, const float* __restrict__ pitch,
                       ll T, ll S, double ratio, char* wsb,
                       const unsigned* __restrict__ f0bits, int cached) {
  Ctrl* c = (Ctrl*)wsb;
  float mean = c->mean32;
  __shared__ unsigned smax[256]; __shared__ unsigned smin[256]; __shared__ int scnt[256];
  unsigned mymax = 0u, mymin = 0xFFFFFFFFu; int mycnt = 0;
  ll stride = (ll)gridDim.x * blockDim.x;
  for (ll t = (ll)blockIdx.x * blockDim.x + threadIdx.x; t < T; t += stride) {
    float xv = xval(snd, mean, t);
    unsigned ab = __float_as_uint(fabsf(xv));
    if (ab > mymax) mymax = ab;
    float f = cached ? __uint_as_float(f0bits[t]) : f0_at(pitch, t, S, ratio);
    bool pos = (f > 0.0f);
    if (pos) { ++mycnt; unsigned fb = __float_as_uint(f); if (fb < mymin) mymin = fb; }
    if (t >= 1) {
      float fp = cached ? __uint_as_float(f0bits[t - 1]) : f0_at(pitch, t - 1, S, ratio);
      bool posp = (fp > 0.0f);
      if (pos && (t == 1 || !posp)) {
        int id = atomicAdd(&c->n_starts, 1);
        if (id < MAXR) c->region_start[id] = (int)t;
      }
      if (!pos && posp && (t - 1) >= 1) {
        int id = atomicAdd(&c->n_ends, 1);
        if (id < MAXR) c->region_end[id] = (int)t;
      }
    }
    if (t == T - 1 && pos) {
      int id = atomicAdd(&c->n_ends, 1);
      if (id < MAXR) c->region_end[id] = (int)T;
    }
  }
  smax[threadIdx.x] = mymax; smin[threadIdx.x] = mymin; scnt[threadIdx.x] = mycnt;
  __syncthreads();
  for (int o = 128; o > 0; o >>= 1) {
    if ((int)threadIdx.x < o) {
      if (smax[threadIdx.x + o] > smax[threadIdx.x]) smax[threadIdx.x] = smax[threadIdx.x + o];
      if (smin[threadIdx.x + o] < smin[threadIdx.x]) smin[threadIdx.x] = smin[threadIdx.x + o];
      scnt[threadIdx.x] += scnt[threadIdx.x + o];
    }
    __syncthreads();
  }
  if (threadIdx.x == 0) {
    atomicMax(&c->amax_bits, smax[0]);
    atomicMin(&c->minf0_bits, smin[0]);
    atomicAdd(&c->cnt_pos, scnt[0]);
  }
}

__global__ void k_prep(char* wsb, const float* ps) {
  Ctrl* c = (Ctrl*)wsb;
  int ns = c->n_starts; if (ns > MAXR) ns = MAXR;
  int ne = c->n_ends; if (ne > MAXR) ne = MAXR;
  for (int a = 1; a < ns; ++a) {
    int v = c->region_start[a]; int b = a - 1;
    while (b >= 0 && c->region_start[b] > v) { c->region_start[b + 1] = c->region_start[b]; --b; }
    c->region_start[b + 1] = v;
  }
  for (int a = 1; a < ne; ++a) {
    int v = c->region_end[a]; int b = a - 1;
    while (b >= 0 && c->region_end[b] > v) { c->region_end[b + 1] = c->region_end[b]; --b; }
    c->region_end[b + 1] = v;
  }
  int nr = ns < ne ? ns : ne;
  c->nregions = nr;
  c->tail = (nr > 0) ? (ll)c->region_end[nr - 1] : 0;
  c->gpeak = (double)__uint_as_float(c->amax_bits);
  ll cnt = (ll)c->cnt_pos; if (cnt < 1) cnt = 1;
  c->k_rem = (cnt - 1) / 2;
  c->prefix = 0u; c->shift = 24;
  c->slab = MAXOPS / (nr > 0 ? nr : 1);
  double p64 = (double)ps[0];
  c->ps64 = round(p64 * 1e7) / 1e7;
}

__global__ void k_hist(const float* __restrict__ pitch, ll T, ll S, double ratio, char* wsb,
                       const unsigned* __restrict__ f0bits, int cached) {
  Ctrl* c = (Ctrl*)wsb;
  __shared__ int h[256];
  for (int b = threadIdx.x; b < 256; b += blockDim.x) h[b] = 0;
  __syncthreads();
  int shift = c->shift;
  unsigned pref = c->prefix;
  unsigned himask = (shift == 24) ? 0u : ((~0u) << (shift + 8));
  ll stride = (ll)gridDim.x * blockDim.x;
  for (ll t = (ll)blockIdx.x * blockDim.x + threadIdx.x; t < T; t += stride) {
    float f; unsigned bits;
    if (cached) { bits = f0bits[t]; f = __uint_as_float(bits); }
    else { f = f0_at(pitch, t, S, ratio); bits = __float_as_uint(f); }
    if (f > 0.0f) {
      if ((bits & himask) == (pref & himask)) atomicAdd(&h[(bits >> shift) & 255], 1);
    }
  }
  __syncthreads();
  for (int b = threadIdx.x; b < 256; b += blockDim.x) if (h[b]) atomicAdd(&c->hist[b], h[b]);
}

__global__ void k_sel(char* wsb, const float* ps, const float* pr) {
  Ctrl* c = (Ctrl*)wsb;
  int shift = c->shift;
  ll k = c->k_rem;
  ll run = 0; int pick = 255;
  for (int b = 0; b < 256; ++b) {
    ll h = (ll)c->hist[b];
    if (run + h > k) { pick = b; break; }
    run += h;
  }
  c->prefix |= ((unsigned)pick) << shift;
  c->k_rem = k - run;
  for (int b = 0; b < 256; ++b) c->hist[b] = 0;
  if (shift == 0) {
    float mraw = __uint_as_float(c->prefix);
    c->median_raw = mraw;
    double md = dmul((double)mraw, c->ps64);
    float md32 = (float)md;
    c->md32 = md32;
    float minf = __uint_as_float(c->minf0_bits);
    float u = fmul(minf, ps[0]);
    float sc = fadd(md32, fmul(fsub(u, md32), pr[0]));
    c->minv_scaled32 = sc;
    c->max_w = 20000.0 / (double)sc;
  }
  c->shift = shift - 8;
}

#define WALK_MAXI 400000
#define WPS 1664

// One wave per chain; conditional pipelined register staging; LDS pitch slab;
// fused 3-stream norms; fused dual-slot dot with vectorized tm; Markstein div;
// butterfly argmax.
__global__ __launch_bounds__(64) void k_walks(const float* __restrict__ snd,
                                              const float* __restrict__ pitch,
                                              ll T, ll S, double ratio, char* wsb) {
  Ctrl* c = (Ctrl*)wsb;
  int chain = blockIdx.x;
  int reg = chain >> 1, dir = chain & 1;  // dir 0 = left walk, 1 = right walk
  if (reg >= c->nregions) return;
  int* mybuf = ((int*)(wsb + CHAINS_OFF)) + (ll)chain * MAXCHAIN;
  ll left = (ll)c->region_start[reg];
  ll right = (ll)c->region_end[reg];
  float mean = c->mean32;
  double gpeak = c->gpeak;
  int lane = threadIdx.x;

  __shared__ __align__(16) float lx[640];     // staged mean-subtracted window
  __shared__ __align__(16) float ltm[272];    // normalized template
  __shared__ float lpitch[WPS];               // pitch frames for this region

  // stage pitch frames covering f0 reads at t in [left, right]
  ll tA = left - 600; if (tA < 0) tA = 0;
  ll tB = right + 600; if (tB > T - 1) tB = T - 1;
  ll p0l = frame_lo(tA, S, ratio);
  ll p1l = frame_lo(tB, S, ratio) + 1; if (p1l > S - 1) p1l = S - 1;
  int p0 = (int)p0l, p1 = (int)p1l;
  int span = p1 - p0 + 1;
  bool puse = (span <= WPS);
  if (puse) {
    for (int k = lane; k < span; k += 64) lpitch[k] = pitch[p0 + k];
  } else { p0 = 0; p1 = -1; }  // force global fallback inside f0_lds
  __syncthreads();

  // initial position (all lanes redundantly; identical deterministic arithmetic)
  ll i;
  {
    ll middle = (left + right) / 2;
    float f0m = f0_lds(lpitch, p0, p1, pitch, middle, S, ratio);
    int w0 = (int)(16000.0 / (double)f0m);
    ll s0 = middle - (ll)(w0 / 2); if (s0 < 0) s0 = 0;
    ll len = T - s0; if (len > (ll)w0) len = (ll)w0;
    float mn = 0.f, mx = 0.f; ll imn = 0, imx = 0; bool first = true;
    for (ll k = 0; k < len; ++k) {
      float v = xval(snd, mean, s0 + k);
      if (first) { mn = mx = v; imn = imx = 0; first = false; }
      else {
        if (v < mn) { mn = v; imn = k; }
        if (v > mx) { mx = v; imx = k; }
      }
    }
    if (mn == mx) i = middle;
    else i = s0 + ((fabs((double)mn) > fabs((double)mx)) ? imn : imx);
  }

  double added_right = -1e308;
  int cnt = 0;
  bool stop = false;

  for (int iter = 0; iter < WALK_MAXI && !stop; ++iter) {
    float f0v = f0_lds(lpitch, p0, p1, pitch, i, S, ratio);
    int w = (int)(16000.0 / fmax((double)f0v, 60.0));  // <= 266
    ll cl, cr;
    if (dir == 0) {
      cl = (ll)dsub((double)i, dmul(1.75, (double)w)); if (cl < 0) cl = 0;
      cr = (ll)dsub((double)i, dmul(1.3, (double)w)); if (cr < 0) cr = 0;
    } else {
      cl = (ll)dadd((double)i, dmul(0.3, (double)w));
      cr = (ll)dadd((double)i, dmul(0.75, (double)w));
    }
    ll s = i - (ll)(w / 2); if (s < 0) s = 0;
    bool valid = !(cl == cr || (T - cl) < (ll)w || (s + (ll)w) > T);
    double corrd; ll ipos; double peakd;
    if (!valid) { corrd = -1.0; ipos = i; peakd = 0.0; }
    else {
      ll L = cr + (ll)w; if (L > T) L = T; L -= cl;
      int ncand = (int)(L - (ll)w + 1);           // 1..121
      // stage window [lo, hi) into LDS, mean-subtracted; len <= 599
      ll lo = (s < cl) ? s : cl;
      ll hiA = s + (ll)w;
      ll hiB = cl + L;
      ll hi = (hiA > hiB) ? hiA : hiB;
      int len = (int)(hi - lo);
      bool big = (len > 320);
      // phase 1: issue loads (pipelined; clamped addresses stay in-bounds)
      float stg[10];
      #pragma unroll
      for (int j = 0; j < 5; ++j) {
        ll a = lo + (ll)(j * 64) + lane;
        if (a > T - 1) a = T - 1;
        stg[j] = snd[a];
      }
      if (big) {
        #pragma unroll
        for (int j = 5; j < 10; ++j) {
          ll a = lo + (ll)(j * 64) + lane;
          if (a > T - 1) a = T - 1;
          stg[j] = snd[a];
        }
      }
      __syncthreads();  // guard vs previous iteration's LDS reads
      // phase 2: write to LDS (single drain for all loads)
      #pragma unroll
      for (int j = 0; j < 5; ++j) {
        int k = j * 64 + lane;
        if (k < len) lx[k] = fsub(stg[j], mean);
      }
      if (big) {
        #pragma unroll
        for (int j = 5; j < 10; ++j) {
          int k = j * 64 + lane;
          if (k < len) lx[k] = fsub(stg[j], mean);
        }
      }
      __syncthreads();
      int toff = (int)(s - lo);
      int coff = (int)(cl - lo);
      // fused template + slot-0 + optional slot-1 norms
      int r0 = lane;
      int rc0 = (r0 < ncand) ? r0 : (ncand - 1);
      bool has1 = (ncand > 64);
      int rc1 = 0;
      if (has1) { int r1v = lane + 64; rc1 = (r1v < ncand) ? r1v : (ncand - 1); }
      float pk0 = 0.0f, pk1 = 0.0f;
      float tsq, csq0, csq1 = 0.0f;
      if (has1) pw3_sq<true>(lx, toff, coff + rc0, coff + rc1, w, tsq, csq0, csq1, pk0, pk1);
      else      pw3_sq<false>(lx, toff, coff + rc0, 0, w, tsq, csq0, csq1, pk0, pk1);
      float tn = __fsqrt_rn(tsq);
      float tdiv = (float)fmax((double)tn, 1e-12);
      float rt = __fdiv_rn(1.0f, tdiv);
      float nr0 = __fsqrt_rn(csq0);
      float divr0 = fmaxf(nr0, (float)1e-12);
      float rr0 = __fdiv_rn(1.0f, divr0);
      float divr1 = 1.0f, rr1 = 1.0f;
      if (has1) {
        float nr1 = __fsqrt_rn(csq1);
        divr1 = fmaxf(nr1, (float)1e-12);
        rr1 = __fdiv_rn(1.0f, divr1);
      }
      // normalized template -> LDS (Markstein division == __fdiv_rn bitwise)
      for (int k = lane; k < w; k += 64) ltm[k] = div_exact(lx[toff + k], tdiv, rt);
      __syncthreads();
      // fused dual-slot dots
      float co0, co1;
      if (has1) dot2_lds<true>(lx, coff + rc0, coff + rc1, divr0, rr0, divr1, rr1, ltm, w, co0, co1);
      else      dot2_lds<false>(lx, coff + rc0, 0, divr0, rr0, divr1, rr1, ltm, w, co0, co1);
      if (has1 && (lane + 64 >= ncand)) co1 = -INFINITY;
      // fold slots (prefer higher corr; ties -> lower index)
      float bv = (r0 < ncand) ? co0 : -INFINITY;
      int bi = (r0 < ncand) ? r0 : 0x7FFFFFFF;
      {
        int i1 = lane + 64;
        if (co1 > bv || (co1 == bv && i1 < bi)) { bv = co1; bi = i1; }
      }
      // butterfly argmax (first-occurrence tie-break, matches serial scan)
      for (int off = 32; off > 0; off >>= 1) {
        float ov = __shfl_xor(bv, off);
        int oi = __shfl_xor(bi, off);
        if (ov > bv || (ov == bv && oi < bi)) { bv = ov; bi = oi; }
      }
      corrd = (double)bv;
      ipos = i + ((ll)bi + cl) - s;
      {
        int ol = bi & 63;
        float p0f = __shfl(pk0, ol);
        float p1f = __shfl(pk1, ol);
        peakd = (double)((bi < 64) ? p0f : p1f);
      }
    }
    // decision (all lanes redundantly; lane 0 writes)
    ll inew;
    if (dir == 0) {
      inew = (corrd == -1.0) ? (i - (ll)w) : ipos;
      if (inew < left) {
        if (corrd > 0.7 && peakd > dmul(0.023333, gpeak) &&
            (dsub((double)inew, added_right) > dmul(0.8, (double)w))) {
          if (cnt < MAXCHAIN) { if (lane == 0) mybuf[cnt] = (int)inew; ++cnt; }
        }
        stop = true;
      } else {
        if (corrd > 0.3 && (peakd == 0.0 || peakd > dmul(0.01, gpeak))) {
          if (dsub((double)inew, added_right) > dmul(0.8, (double)w)) {
            if (cnt < MAXCHAIN) { if (lane == 0) mybuf[cnt] = (int)inew; ++cnt; }
          }
        }
        i = inew;
      }
    } else {
      inew = (corrd == -1.0) ? (i + (ll)w) : ipos;
      if (inew >= right) {
        if (corrd > 0.7 && peakd > dmul(0.023333, gpeak)) {
          if (cnt < MAXCHAIN) { if (lane == 0) mybuf[cnt] = (int)inew; ++cnt; }
        }
        stop = true;
      } else {
        if (corrd > 0.3 && (peakd == 0.0 || peakd > dmul(0.01, gpeak))) {
          if (cnt < MAXCHAIN) { if (lane == 0) mybuf[cnt] = (int)inew; ++cnt; }
          added_right = (double)inew;
        }
        i = inew;
      }
    }
  }
  if (lane == 0) c->chain_cnt[chain] = cnt;
}

__global__ void k_offsets(char* wsb) {
  Ctrl* c = (Ctrl*)wsb;
  int off = 0;
  for (int ch = 0; ch < 128; ++ch) {
    c->chain_off[ch] = off;
    off += c->chain_cnt[ch];
  }
  c->chain_off[128] = off;
  c->n_peaks = (off > MAXP) ? MAXP : off;
}

__global__ void k_gather(char* wsb, ll T) {
  Ctrl* c = (Ctrl*)wsb;
  int chain = blockIdx.x;
  int cnt = c->chain_cnt[chain];
  int off = c->chain_off[chain];
  const int* mybuf = ((const int*)(wsb + CHAINS_OFF)) + (ll)chain * MAXCHAIN;
  int* peaks = (int*)(wsb + PEAKS_OFF);
  int dir = chain & 1;
  for (int k = threadIdx.x; k < cnt; k += blockDim.x) {
    if (off + k < MAXP) {
      int v = dir ? mybuf[k] : mybuf[cnt - 1 - k];  // left chains stored descending
      if (v < 0) v = 0;
      if ((ll)v > T - 1) v = (int)(T - 1);
      peaks[off + k] = v;
    }
  }
}

#define PSLDS 3584
#define PPS 2048

__global__ __launch_bounds__(64) void k_psola(const float* __restrict__ pitch, ll T, ll S,
                                              double ratio, char* wsb,
                                              const float* ps, const float* pr) {
  Ctrl* c = (Ctrl*)wsb;
  int r = blockIdx.x;
  if (r >= c->nregions) return;
  const int* peaks = (const int*)(wsb + PEAKS_OFF);
  int np = c->n_peaks;
  int tid = threadIdx.x;
  ll left = (ll)c->region_start[r], right = (ll)c->region_end[r];

  __shared__ int lp[PSLDS];
  __shared__ float lpitch[PPS];
  __shared__ int sh_g0, sh_g1, sh_use;

  // stage pitch frames for f0 reads at lv in [left, right)
  ll tA = left - 600; if (tA < 0) tA = 0;
  ll tB = right + 600; if (tB > T - 1) tB = T - 1;
  ll p0l = frame_lo(tA, S, ratio);
  ll p1l = frame_lo(tB, S, ratio) + 1; if (p1l > S - 1) p1l = S - 1;
  int p0 = (int)p0l, p1 = (int)p1l;
  int span = p1 - p0 + 1;
  if (span <= PPS) {
    for (int k = tid; k < span; k += 64) lpitch[k] = pitch[p0 + k];
  } else { p0 = 0; p1 = -1; }

  if (np > 0) {
    if (tid == 0) {
      int lo = 0, hi = np;
      ll tgt = left - 512;
      while (lo < hi) { int m = (lo + hi) >> 1; if ((ll)peaks[m] < tgt) lo = m + 1; else hi = m; }
      int a = lo;
      lo = 0; hi = np; tgt = right + 512;
      while (lo < hi) { int m = (lo + hi) >> 1; if ((ll)peaks[m] < tgt) lo = m + 1; else hi = m; }
      int b = lo;
      a -= 4; if (a < 0) a = 0;
      b += 4; if (b > np) b = np;
      sh_g0 = a; sh_g1 = b; sh_use = (b - a <= PSLDS) ? 1 : 0;
    }
    __syncthreads();
    if (sh_use) {
      for (int k = sh_g0 + tid; k < sh_g1; k += 64) lp[k - sh_g0] = peaks[k];
    }
  }
  __syncthreads();
  if (tid != 0) return;

  int g0 = (np > 0 && sh_use) ? sh_g0 : 0;
  const int* pk = (np > 0 && sh_use) ? lp : peaks;

  int slab = c->slab;
  int4* myops = ((int4*)(wsb + OPS_OFF)) + (ll)r * slab;
  int cnt = 0;
  ll prev_end = (r == 0) ? 0 : (ll)c->region_end[r - 1];
  ll lv = left, rv = right;
  double max_w = c->max_w;
  float md32 = c->md32, psv = ps[0], prv = pr[0];

  ll gapn = lv - prev_end;
  if (gapn > 0) {
    if (cnt < slab) myops[cnt] = make_int4((int)prev_end, (int)prev_end, (int)gapn, (int)gapn);
    ++cnt;
  }
  if (np > 0) {
    int j;
    {
      int loJ = 0, hiJ = np;
      while (loJ < hiJ) {
        int mid = (loJ + hiJ) >> 1;
        if ((ll)peaks[mid] < lv) loJ = mid + 1; else hiJ = mid;
      }
      j = loJ;
    }
    for (long itc = 0; itc < 2000000 && lv < rv; ++itc) {
      float f = f0_lds(lpitch, p0, p1, pitch, lv, S, ratio);
      float u = fmul(f, psv);
      float fs = (!(u > 0.0f)) ? 0.0f : fadd(md32, fmul(fsub(u, md32), prv));
      int period = (int)(16000.0 / fmax((double)fs, 60.0));
      int lw = period / 2, rw = period / 2;
      while (j < np && (ll)pk[j - g0] < lv) ++j;
      ll dl = (j > 0) ? (lv - (ll)pk[j - 1 - g0]) : LLONG_MAX;
      ll dr = (j < np) ? ((ll)pk[j - g0] - lv) : LLONG_MAX;
      int p;
      if (dl <= dr) {
        int q = j - 1; int v = pk[q - g0];
        while (q > 0 && pk[q - 1 - g0] == v) --q;
        p = q;
      } else {
        int q = j; int v = pk[q - g0];
        while (q > 0 && pk[q - 1 - g0] == v) --q;
        p = q;
      }
      if (p > 0) {
        ll g = (ll)pk[p - g0] - (ll)pk[p - 1 - g0];
        if ((double)g <= max_w && g < (ll)lw) lw = (int)g;
      }
      if (p < np - 1) {
        ll g = (ll)pk[p + 1 - g0] - (ll)pk[p - g0];
        if ((double)g <= max_w && g < (ll)rw) rw = (int)g;
      }
      ll li = (ll)pk[p - g0] - (ll)lw; if (li < 0) li = 0;
      ll ri = (ll)pk[p - g0] + (ll)rw;
      ll ival = (ri - li) / 2;
      if (ival <= 0) { lv += (period > 1 ? (ll)period : 1); continue; }
      ll a = lv - ival, b = lv + ival;
      ll st = (a < 0) ? ((a + T > 0) ? a + T : 0) : ((a < T) ? a : T);
      ll sp = (b < 0) ? ((b + T > 0) ? b + T : 0) : ((b < T) ? b : T);
      ll dst_len = sp - st; if (dst_len < 0) dst_len = 0;
      ll se = li + 2 * ival; if (se > T) se = T;
      ll src_len = se - li; if (src_len < 0) src_len = 0;
      ll seglen = dst_len < src_len ? dst_len : src_len;
      if (seglen > 0) {
        if (cnt < slab) myops[cnt] = make_int4((int)st, (int)li, (int)seglen, (int)(2 * ival));
        ++cnt;
      }
      lv += 2 * ival;
    }
  }
  c->region_ops[r] = (cnt > slab) ? slab : cnt;
}

__global__ void k_scatter(const float* __restrict__ snd, char* wsb, float* out, ll T) {
  Ctrl* c = (Ctrl*)wsb;
  float mean = c->mean32;
  int nr = c->nregions; if (nr > MAXR) nr = MAXR;
  int slab = c->slab;
  const int4* ops = (const int4*)(wsb + OPS_OFF);
  ll total = (ll)nr * slab;
  for (ll idx = blockIdx.x; idx < total; idx += gridDim.x) {
    int r = (int)(idx / slab);
    int o = (int)(idx - (ll)r * slab);
    if (o >= c->region_ops[r]) continue;
    int4 op = ops[(ll)r * slab + o];
    ll dst = (ll)op.x, src = (ll)op.y; int n = op.z, m = op.w;
    for (int k = threadIdx.x; k < n; k += blockDim.x) {
      double ang = dmul(TWOPI, (double)k) / (double)m;
      float w32 = (float)dsub(0.5, dmul(0.5, cos(ang)));
      float val = fmul(w32, xval(snd, mean, src + k));
      atomicAdd(&out[dst + k], val);
    }
  }
}

__global__ void k_final(const float* __restrict__ snd, char* wsb, float* out, ll T) {
  Ctrl* c = (Ctrl*)wsb;
  float mean = c->mean32;
  ll tail = c->tail;
  ll stride = (ll)gridDim.x * blockDim.x;
  for (ll t = (ll)blockIdx.x * blockDim.x + threadIdx.x; t < T; t += stride)
    if (t >= tail) out[t] = xval(snd, mean, t);
}

extern "C" void kernel_launch(void* const* d_in, const int* in_sizes, int n_in,
                              void* d_out, int out_size, void* d_ws, size_t ws_size,
                              hipStream_t stream) {
  ll T = (ll)in_sizes[0];
  ll S = (ll)in_sizes[1];
  const float* snd = (const float*)d_in[0];
  const float* pitch = (const float*)d_in[1];
  const float* ps = (const float*)d_in[2];
  const float* pr = (const float*)d_in[3];
  float* out = (float*)d_out;
  char* wsb = (char*)d_ws;
  double ratio = (double)S / (double)T;

  size_t f0_need = F0_OFF + (size_t)T * 4;
  int cached = (ws_size >= f0_need) ? 1 : 0;
  unsigned* f0bits = (unsigned*)(wsb + F0_OFF);

  k_init<<<1, 256, 0, stream>>>(wsb);
  k_sum_partial<<<1024, 256, 0, stream>>>(snd, T, wsb);
  k_sum_final<<<1, 256, 0, stream>>>(wsb, T, 1024);
  if (cached) k_f0<<<2048, 256, 0, stream>>>(pitch, T, S, ratio, f0bits);
  k_scan<<<2048, 256, 0, stream>>>(snd, pitch, T, S, ratio, wsb, f0bits, cached);
  k_prep<<<1, 1, 0, stream>>>(wsb, ps);
  for (int pass = 0; pass < 4; ++pass) {
    k_hist<<<2048, 256, 0, stream>>>(pitch, T, S, ratio, wsb, f0bits, cached);
    k_sel<<<1, 1, 0, stream>>>(wsb, ps, pr);
  }
  k_walks<<<128, 64, 0, stream>>>(snd, pitch, T, S, ratio, wsb);
  k_offsets<<<1, 1, 0, stream>>>(wsb);
  k_gather<<<128, 64, 0, stream>>>(wsb, T);
  k_psola<<<64, 64, 0, stream>>>(pitch, T, S, ratio, wsb, ps, pr);
  hipMemsetAsync(d_out, 0, (size_t)out_size * sizeof(float), stream);
  k_scatter<<<8192, 128, 0, stream>>>(snd, wsb, out, T);
  k_final<<<2048, 256, 0, stream>>>(snd, wsb, out, T);
}

// Round 8
// 11625.022 us; speedup vs baseline: 1.0319x; 1.0319x over previous
//
#include <hip/hip_runtime.h>
#include <math.h>
#include <limits.h>

typedef long long ll;

#define MAXCHAIN 4096
#define MAXP 49152
#define MAXOPS 49152
#define MAXR 64
#define PART_OFF 4096
#define CHAINS_OFF 16384
#define PEAKS_OFF (CHAINS_OFF + 128 * MAXCHAIN * 4)
#define OPS_OFF (PEAKS_OFF + MAXP * 4)
#define F0_OFF (OPS_OFF + (size_t)MAXOPS * 16)

static __device__ const double TWOPI = 6.283185307179586;

struct Ctrl {
  double gpeak, max_w, ps64;
  long long k_rem, tail;
  float mean32, median_raw, md32, minv_scaled32;
  unsigned amax_bits, minf0_bits, prefix;
  int cnt_pos, shift, n_starts, n_ends, nregions, n_peaks, n_ops, slab;
  int hist[256];
  int region_start[MAXR], region_end[MAXR];
  int chain_cnt[128];
  int chain_off[129];
  int region_ops[MAXR];
};

// LDS-ordering barrier that does NOT drain vmcnt (keeps prefetch loads in
// flight). lgkmcnt(0) orders ds ops; sched_barrier pins scheduling (rule #18).
#define WBAR() do { \
  asm volatile("s_waitcnt lgkmcnt(0)" ::: "memory"); \
  __builtin_amdgcn_s_barrier(); \
  __builtin_amdgcn_sched_barrier(0); \
} while (0)

// ---------- exact-arith helpers (no FMA contraction) ----------
__device__ __forceinline__ double dmul(double a, double b) { return __dmul_rn(a, b); }
__device__ __forceinline__ double dadd(double a, double b) { return __dadd_rn(a, b); }
__device__ __forceinline__ double dsub(double a, double b) { return __dadd_rn(a, -b); }
__device__ __forceinline__ float fmul(float a, float b) { return __fmul_rn(a, b); }
__device__ __forceinline__ float fadd(float a, float b) { return __fadd_rn(a, b); }
__device__ __forceinline__ float fsub(float a, float b) { return __fadd_rn(a, -b); }

__device__ __forceinline__ float xval(const float* snd, float mean, ll t) {
  return fsub(snd[t], mean);
}

// Markstein correctly-rounded division: r = RN(1/d) precomputed.
__device__ __forceinline__ float div_exact(float x, float d, float r) {
  float q = __fmul_rn(x, r);
  float e = __fmaf_rn(-d, q, x);
  return __fmaf_rn(e, r, q);
}

// f0 = linear interp of pitch, computed exactly as numpy (f64 ops, one f32 round)
__device__ float f0_at(const float* pitch, ll t, ll S, double ratio) {
  double pos = dsub(dmul(dadd((double)t, 0.5), ratio), 0.5);
  double hi = (double)(S - 1);
  pos = fmin(fmax(pos, 0.0), hi);
  double fl = floor(pos);
  ll lo = (ll)fl;
  if (lo < 0) lo = 0;
  if (lo > S - 1) lo = S - 1;
  ll hii = lo + 1; if (hii > S - 1) hii = S - 1;
  double frac = dsub(pos, fl);
  double om = dsub(1.0, frac);
  double v = dadd(dmul((double)pitch[lo], om), dmul((double)pitch[hii], frac));
  return (float)v;
}

// frame index used by f0 interp at time t
__device__ __forceinline__ ll frame_lo(ll t, ll S, double ratio) {
  double pos = dsub(dmul(dadd((double)t, 0.5), ratio), 0.5);
  pos = fmin(fmax(pos, 0.0), (double)(S - 1));
  ll lo = (ll)floor(pos);
  if (lo < 0) lo = 0;
  if (lo > S - 1) lo = S - 1;
  return lo;
}

// identical arithmetic to f0_at; pitch values served from LDS slab [p0..p1]
__device__ __forceinline__ float f0_lds(const float* __restrict__ lpitch, int p0, int p1,
                                        const float* __restrict__ pitch,
                                        ll t, ll S, double ratio) {
  double pos = dsub(dmul(dadd((double)t, 0.5), ratio), 0.5);
  pos = fmin(fmax(pos, 0.0), (double)(S - 1));
  double fl = floor(pos);
  ll lo = (ll)fl;
  if (lo < 0) lo = 0;
  if (lo > S - 1) lo = S - 1;
  ll hii = lo + 1; if (hii > S - 1) hii = S - 1;
  double frac = dsub(pos, fl);
  double om = dsub(1.0, frac);
  float plo = (lo >= p0 && lo <= p1) ? lpitch[(int)(lo - p0)] : pitch[lo];
  float phi = (hii >= p0 && hii <= p1) ? lpitch[(int)(hii - p0)] : pitch[hii];
  return (float)dadd(dmul((double)plo, om), dmul((double)phi, frac));
}

// ---- fused pairwise sum-of-squares for TWO same-length ranges (A: no pk, B: pk).
// Software-pipelined LDS loads; per-range arithmetic order identical to numpy's
// 8-accumulator pairwise scheme (chains independent -> fusion changes nothing).
__device__ void pw2_blk(const float* __restrict__ buf, int bA, int bB, int n,
                        float& outA, float& outB, float& pkB) {
  if (n < 8) {
    float ra = 0.f;
    for (int i = 0; i < n; ++i) { float x = buf[bA + i]; ra = fadd(ra, fmul(x, x)); }
    float rb = 0.f;
    for (int i = 0; i < n; ++i) {
      float x = buf[bB + i];
      pkB = fmaxf(pkB, fabsf(x));
      rb = fadd(rb, fmul(x, x));
    }
    outA = ra; outB = rb; return;
  }
  float ca[8], cb[8], na[8], nb[8], rA[8], rB[8];
  #pragma unroll
  for (int j = 0; j < 8; ++j) ca[j] = buf[bA + j];
  #pragma unroll
  for (int j = 0; j < 8; ++j) cb[j] = buf[bB + j];
  int lim = n - (n & 7);
  bool hn = (8 < lim);
  if (hn) {
    #pragma unroll
    for (int j = 0; j < 8; ++j) na[j] = buf[bA + 8 + j];
    #pragma unroll
    for (int j = 0; j < 8; ++j) nb[j] = buf[bB + 8 + j];
  }
  #pragma unroll
  for (int j = 0; j < 8; ++j) pkB = fmaxf(pkB, fabsf(cb[j]));
  #pragma unroll
  for (int j = 0; j < 8; ++j) rA[j] = fmul(ca[j], ca[j]);
  #pragma unroll
  for (int j = 0; j < 8; ++j) rB[j] = fmul(cb[j], cb[j]);
  for (int i = 8; i < lim; i += 8) {
    #pragma unroll
    for (int j = 0; j < 8; ++j) { ca[j] = na[j]; cb[j] = nb[j]; }
    bool hn2 = (i + 8 < lim);
    if (hn2) {
      #pragma unroll
      for (int j = 0; j < 8; ++j) na[j] = buf[bA + i + 8 + j];
      #pragma unroll
      for (int j = 0; j < 8; ++j) nb[j] = buf[bB + i + 8 + j];
    }
    #pragma unroll
    for (int j = 0; j < 8; ++j) {
      pkB = fmaxf(pkB, fabsf(cb[j]));
      rA[j] = fadd(rA[j], fmul(ca[j], ca[j]));
      rB[j] = fadd(rB[j], fmul(cb[j], cb[j]));
    }
  }
  float resA = fadd(fadd(fadd(rA[0], rA[1]), fadd(rA[2], rA[3])),
                    fadd(fadd(rA[4], rA[5]), fadd(rA[6], rA[7])));
  float resB = fadd(fadd(fadd(rB[0], rB[1]), fadd(rB[2], rB[3])),
                    fadd(fadd(rB[4], rB[5]), fadd(rB[6], rB[7])));
  for (int i = lim; i < n; ++i) {
    float xa = buf[bA + i];
    resA = fadd(resA, fmul(xa, xa));
    float xb = buf[bB + i];
    pkB = fmaxf(pkB, fabsf(xb));
    resB = fadd(resB, fmul(xb, xb));
  }
  outA = resA; outB = resB;
}

__device__ void pw2_sq(const float* __restrict__ buf, int bA, int bB, int n,
                       float& oA, float& oB, float& pkB) {
  if (n <= 128) { pw2_blk(buf, bA, bB, n, oA, oB, pkB); return; }
  int n2 = (n >> 1); n2 -= (n2 & 7);
  float a1, b1;
  pw2_blk(buf, bA, bB, n2, a1, b1, pkB);
  int m = n - n2;
  if (m <= 128) {
    float a2, b2;
    pw2_blk(buf, bA + n2, bB + n2, m, a2, b2, pkB);
    oA = fadd(a1, a2); oB = fadd(b1, b2);
  } else {
    int m2 = (m >> 1); m2 -= (m2 & 7);
    float a2a, b2a, a2b, b2b;
    pw2_blk(buf, bA + n2, bB + n2, m2, a2a, b2a, pkB);
    pw2_blk(buf, bA + n2 + m2, bB + n2 + m2, m - m2, a2b, b2b, pkB);
    oA = fadd(a1, fadd(a2a, a2b)); oB = fadd(b1, fadd(b2a, b2b));
  }
}

// single-range pipelined pairwise sum-of-squares + pk (slot-1 candidate norm)
__device__ float pw1_blk(const float* __restrict__ buf, int base, int n, float& pk) {
  if (n < 8) {
    float res = 0.0f;
    for (int i = 0; i < n; ++i) {
      float x = buf[base + i];
      pk = fmaxf(pk, fabsf(x));
      res = fadd(res, fmul(x, x));
    }
    return res;
  }
  float cb[8], nb[8], rB[8];
  #pragma unroll
  for (int j = 0; j < 8; ++j) cb[j] = buf[base + j];
  int lim = n - (n & 7);
  bool hn = (8 < lim);
  if (hn) {
    #pragma unroll
    for (int j = 0; j < 8; ++j) nb[j] = buf[base + 8 + j];
  }
  #pragma unroll
  for (int j = 0; j < 8; ++j) pk = fmaxf(pk, fabsf(cb[j]));
  #pragma unroll
  for (int j = 0; j < 8; ++j) rB[j] = fmul(cb[j], cb[j]);
  for (int i = 8; i < lim; i += 8) {
    #pragma unroll
    for (int j = 0; j < 8; ++j) cb[j] = nb[j];
    bool hn2 = (i + 8 < lim);
    if (hn2) {
      #pragma unroll
      for (int j = 0; j < 8; ++j) nb[j] = buf[base + i + 8 + j];
    }
    #pragma unroll
    for (int j = 0; j < 8; ++j) {
      pk = fmaxf(pk, fabsf(cb[j]));
      rB[j] = fadd(rB[j], fmul(cb[j], cb[j]));
    }
  }
  float res = fadd(fadd(fadd(rB[0], rB[1]), fadd(rB[2], rB[3])),
                   fadd(fadd(rB[4], rB[5]), fadd(rB[6], rB[7])));
  for (int i = lim; i < n; ++i) {
    float y = buf[base + i];
    pk = fmaxf(pk, fabsf(y));
    res = fadd(res, fmul(y, y));
  }
  return res;
}

__device__ float pw1_sq(const float* __restrict__ buf, int base, int n, float& pk) {
  if (n <= 128) return pw1_blk(buf, base, n, pk);
  int n2 = (n >> 1); n2 -= (n2 & 7);
  float a = pw1_blk(buf, base, n2, pk);
  int m = n - n2;
  float b;
  if (m <= 128) {
    b = pw1_blk(buf, base + n2, m, pk);
  } else {
    int m2 = (m >> 1); m2 -= (m2 & 7);
    float b1 = pw1_blk(buf, base + n2, m2, pk);
    float b2 = pw1_blk(buf, base + n2 + m2, m - m2, pk);
    b = fadd(b1, b2);
  }
  return fadd(a, b);
}

// BLAS-sgemv mimic over LDS, software-pipelined. Markstein division.
__device__ float dot_lds(const float* __restrict__ buf, int base, float d, float r,
                         const float* __restrict__ tm, int w) {
  float acc[8];
  #pragma unroll
  for (int j = 0; j < 8; ++j) acc[j] = 0.f;
  int lim = w - (w & 7);
  if (lim > 0) {
    float cs[8], ct[8], ns[8], nt[8];
    #pragma unroll
    for (int j = 0; j < 8; ++j) cs[j] = buf[base + j];
    #pragma unroll
    for (int j = 0; j < 8; ++j) ct[j] = tm[j];
    for (int k = 0; k < lim; k += 8) {
      bool hn = (k + 8 < lim);
      if (hn) {
        #pragma unroll
        for (int j = 0; j < 8; ++j) ns[j] = buf[base + k + 8 + j];
        #pragma unroll
        for (int j = 0; j < 8; ++j) nt[j] = tm[k + 8 + j];
      }
      #pragma unroll
      for (int j = 0; j < 8; ++j)
        acc[j] = __fmaf_rn(div_exact(cs[j], d, r), ct[j], acc[j]);
      if (hn) {
        #pragma unroll
        for (int j = 0; j < 8; ++j) { cs[j] = ns[j]; ct[j] = nt[j]; }
      }
    }
  }
  #pragma unroll
  for (int j = 0; j < 7; ++j)
    if (lim + j < w)
      acc[j] = __fmaf_rn(div_exact(buf[base + lim + j], d, r), tm[lim + j], acc[j]);
  return fadd(fadd(fadd(acc[0], acc[1]), fadd(acc[2], acc[3])),
              fadd(fadd(acc[4], acc[5]), fadd(acc[6], acc[7])));
}

// ---------- kernels ----------
// fused: Ctrl init (block 0) + mean partial sums (all blocks)
__global__ void k_init_sum(const float* __restrict__ snd, ll T, char* wsb) {
  Ctrl* c = (Ctrl*)wsb;
  if (blockIdx.x == 0) {
    int t = threadIdx.x;
    for (int b = t; b < 256; b += blockDim.x) c->hist[b] = 0;
    for (int b = t; b < 128; b += blockDim.x) c->chain_cnt[b] = 0;
    for (int b = t; b < MAXR; b += blockDim.x) c->region_ops[b] = 0;
    if (t == 0) {
      c->amax_bits = 0u; c->minf0_bits = 0xFFFFFFFFu;
      c->cnt_pos = 0; c->n_starts = 0; c->n_ends = 0; c->n_ops = 0;
      c->nregions = 0; c->n_peaks = 0; c->tail = 0; c->slab = MAXOPS;
    }
  }
  __shared__ double sd[256];
  double local = 0.0;
  ll stride = (ll)gridDim.x * blockDim.x;
  for (ll t = (ll)blockIdx.x * blockDim.x + threadIdx.x; t < T; t += stride)
    local += (double)snd[t];
  sd[threadIdx.x] = local; __syncthreads();
  for (int o = 128; o > 0; o >>= 1) {
    if ((int)threadIdx.x < o) sd[threadIdx.x] += sd[threadIdx.x + o];
    __syncthreads();
  }
  if (threadIdx.x == 0) ((double*)(wsb + PART_OFF))[blockIdx.x] = sd[0];
}

__global__ void k_sum_final(char* wsb, ll T, int nparts) {
  __shared__ double sd[256];
  double local = 0.0;
  const double* p = (const double*)(wsb + PART_OFF);
  for (int i = threadIdx.x; i < nparts; i += blockDim.x) local += p[i];
  sd[threadIdx.x] = local; __syncthreads();
  for (int o = 128; o > 0; o >>= 1) {
    if ((int)threadIdx.x < o) sd[threadIdx.x] += sd[threadIdx.x + o];
    __syncthreads();
  }
  if (threadIdx.x == 0) ((Ctrl*)wsb)->mean32 = (float)(sd[0] / (double)T);
}

// fused: scan (computes f0 inline) + writes f0 bits cache for hist passes
__global__ void k_scan(const float* __restrict__ snd, const float* __restrict__ pitch,
                       ll T, ll S, double ratio, char* wsb,
                       unsigned* __restrict__ f0bits, int cached) {
  Ctrl* c = (Ctrl*)wsb;
  float mean = c->mean32;
  __shared__ unsigned smax[256]; __shared__ unsigned smin[256]; __shared__ int scnt[256];
  unsigned mymax = 0u, mymin = 0xFFFFFFFFu; int mycnt = 0;
  ll stride = (ll)gridDim.x * blockDim.x;
  for (ll t = (ll)blockIdx.x * blockDim.x + threadIdx.x; t < T; t += stride) {
    float xv = xval(snd, mean, t);
    unsigned ab = __float_as_uint(fabsf(xv));
    if (ab > mymax) mymax = ab;
    float f = f0_at(pitch, t, S, ratio);
    if (cached) f0bits[t] = __float_as_uint(f);
    bool pos = (f > 0.0f);
    if (pos) { ++mycnt; unsigned fb = __float_as_uint(f); if (fb < mymin) mymin = fb; }
    if (t >= 1) {
      float fp = f0_at(pitch, t - 1, S, ratio);
      bool posp = (fp > 0.0f);
      if (pos && (t == 1 || !posp)) {
        int id = atomicAdd(&c->n_starts, 1);
        if (id < MAXR) c->region_start[id] = (int)t;
      }
      if (!pos && posp && (t - 1) >= 1) {
        int id = atomicAdd(&c->n_ends, 1);
        if (id < MAXR) c->region_end[id] = (int)t;
      }
    }
    if (t == T - 1 && pos) {
      int id = atomicAdd(&c->n_ends, 1);
      if (id < MAXR) c->region_end[id] = (int)T;
    }
  }
  smax[threadIdx.x] = mymax; smin[threadIdx.x] = mymin; scnt[threadIdx.x] = mycnt;
  __syncthreads();
  for (int o = 128; o > 0; o >>= 1) {
    if ((int)threadIdx.x < o) {
      if (smax[threadIdx.x + o] > smax[threadIdx.x]) smax[threadIdx.x] = smax[threadIdx.x + o];
      if (smin[threadIdx.x + o] < smin[threadIdx.x]) smin[threadIdx.x] = smin[threadIdx.x + o];
      scnt[threadIdx.x] += scnt[threadIdx.x + o];
    }
    __syncthreads();
  }
  if (threadIdx.x == 0) {
    atomicMax(&c->amax_bits, smax[0]);
    atomicMin(&c->minf0_bits, smin[0]);
    atomicAdd(&c->cnt_pos, scnt[0]);
  }
}

__global__ void k_prep(char* wsb, const float* ps) {
  Ctrl* c = (Ctrl*)wsb;
  int ns = c->n_starts; if (ns > MAXR) ns = MAXR;
  int ne = c->n_ends; if (ne > MAXR) ne = MAXR;
  for (int a = 1; a < ns; ++a) {
    int v = c->region_start[a]; int b = a - 1;
    while (b >= 0 && c->region_start[b] > v) { c->region_start[b + 1] = c->region_start[b]; --b; }
    c->region_start[b + 1] = v;
  }
  for (int a = 1; a < ne; ++a) {
    int v = c->region_end[a]; int b = a - 1;
    while (b >= 0 && c->region_end[b] > v) { c->region_end[b + 1] = c->region_end[b]; --b; }
    c->region_end[b + 1] = v;
  }
  int nr = ns < ne ? ns : ne;
  c->nregions = nr;
  c->tail = (nr > 0) ? (ll)c->region_end[nr - 1] : 0;
  c->gpeak = (double)__uint_as_float(c->amax_bits);
  ll cnt = (ll)c->cnt_pos; if (cnt < 1) cnt = 1;
  c->k_rem = (cnt - 1) / 2;
  c->prefix = 0u; c->shift = 24;
  c->slab = MAXOPS / (nr > 0 ? nr : 1);
  double p64 = (double)ps[0];
  c->ps64 = round(p64 * 1e7) / 1e7;
}

__global__ void k_hist(const float* __restrict__ pitch, ll T, ll S, double ratio, char* wsb,
                       const unsigned* __restrict__ f0bits, int cached) {
  Ctrl* c = (Ctrl*)wsb;
  __shared__ int h[256];
  for (int b = threadIdx.x; b < 256; b += blockDim.x) h[b] = 0;
  __syncthreads();
  int shift = c->shift;
  unsigned pref = c->prefix;
  unsigned himask = (shift == 24) ? 0u : ((~0u) << (shift + 8));
  ll stride = (ll)gridDim.x * blockDim.x;
  for (ll t = (ll)blockIdx.x * blockDim.x + threadIdx.x; t < T; t += stride) {
    float f; unsigned bits;
    if (cached) { bits = f0bits[t]; f = __uint_as_float(bits); }
    else { f = f0_at(pitch, t, S, ratio); bits = __float_as_uint(f); }
    if (f > 0.0f) {
      if ((bits & himask) == (pref & himask)) atomicAdd(&h[(bits >> shift) & 255], 1);
    }
  }
  __syncthreads();
  for (int b = threadIdx.x; b < 256; b += blockDim.x) if (h[b]) atomicAdd(&c->hist[b], h[b]);
}

__global__ void k_sel(char* wsb, const float* ps, const float* pr) {
  Ctrl* c = (Ctrl*)wsb;
  int shift = c->shift;
  ll k = c->k_rem;
  ll run = 0; int pick = 255;
  for (int b = 0; b < 256; ++b) {
    ll h = (ll)c->hist[b];
    if (run + h > k) { pick = b; break; }
    run += h;
  }
  c->prefix |= ((unsigned)pick) << shift;
  c->k_rem = k - run;
  for (int b = 0; b < 256; ++b) c->hist[b] = 0;
  if (shift == 0) {
    float mraw = __uint_as_float(c->prefix);
    c->median_raw = mraw;
    double md = dmul((double)mraw, c->ps64);
    float md32 = (float)md;
    c->md32 = md32;
    float minf = __uint_as_float(c->minf0_bits);
    float u = fmul(minf, ps[0]);
    float sc = fadd(md32, fmul(fsub(u, md32), pr[0]));
    c->minv_scaled32 = sc;
    c->max_w = 20000.0 / (double)sc;
  }
  c->shift = shift - 8;
}

#define WALK_MAXI 400000
#define WPS 1664
#define PFN 8
#define PFW (PFN * 64)

// One wave per chain; double-buffered LDS window; cross-step speculative
// prefetch; non-draining barriers; fused norms; pipelined dot; Markstein div.
__global__ __launch_bounds__(64) void k_walks(const float* __restrict__ snd,
                                              const float* __restrict__ pitch,
                                              ll T, ll S, double ratio, char* wsb) {
  Ctrl* c = (Ctrl*)wsb;
  int chain = blockIdx.x;
  int reg = chain >> 1, dir = chain & 1;  // dir 0 = left walk, 1 = right walk
  if (reg >= c->nregions) return;
  int* mybuf = ((int*)(wsb + CHAINS_OFF)) + (ll)chain * MAXCHAIN;
  ll left = (ll)c->region_start[reg];
  ll right = (ll)c->region_end[reg];
  float mean = c->mean32;
  double gpeak = c->gpeak;
  int lane = threadIdx.x;

  __shared__ float lxA[640];     // staged window, buffer A
  __shared__ float lxB[640];     // staged window, buffer B
  __shared__ float ltm[272];     // normalized template
  __shared__ float lpitch[WPS];  // pitch frames for this region

  // stage pitch frames covering f0 reads at t in [left, right]
  ll tA = left - 600; if (tA < 0) tA = 0;
  ll tB = right + 600; if (tB > T - 1) tB = T - 1;
  ll p0l = frame_lo(tA, S, ratio);
  ll p1l = frame_lo(tB, S, ratio) + 1; if (p1l > S - 1) p1l = S - 1;
  int p0 = (int)p0l, p1 = (int)p1l;
  int span = p1 - p0 + 1;
  bool puse = (span <= WPS);
  if (puse) {
    for (int k = lane; k < span; k += 64) lpitch[k] = pitch[p0 + k];
  } else { p0 = 0; p1 = -1; }  // force global fallback inside f0_lds
  __syncthreads();

  // initial position (all lanes redundantly; identical deterministic arithmetic)
  ll i;
  {
    ll middle = (left + right) / 2;
    float f0m = f0_lds(lpitch, p0, p1, pitch, middle, S, ratio);
    int w0 = (int)(16000.0 / (double)f0m);
    ll s0 = middle - (ll)(w0 / 2); if (s0 < 0) s0 = 0;
    ll len = T - s0; if (len > (ll)w0) len = (ll)w0;
    float mn = 0.f, mx = 0.f; ll imn = 0, imx = 0; bool first = true;
    for (ll k = 0; k < len; ++k) {
      float v = xval(snd, mean, s0 + k);
      if (first) { mn = mx = v; imn = imx = 0; first = false; }
      else {
        if (v < mn) { mn = v; imn = k; }
        if (v > mx) { mx = v; imx = k; }
      }
    }
    if (mn == mx) i = middle;
    else i = s0 + ((fabs((double)mn) > fabs((double)mx)) ? imn : imx);
  }

  double added_right = -1e308;
  int cnt = 0;
  bool stop = false;
  int bsel = 0;
  // cross-step prefetch state
  float pstg[PFN];
  ll pf_base = 0;
  bool pf_ok = false;

  for (int iter = 0; iter < WALK_MAXI && !stop; ++iter) {
    float f0v = f0_lds(lpitch, p0, p1, pitch, i, S, ratio);
    int w = (int)(16000.0 / fmax((double)f0v, 60.0));  // <= 266
    ll cl, cr;
    if (dir == 0) {
      cl = (ll)dsub((double)i, dmul(1.75, (double)w)); if (cl < 0) cl = 0;
      cr = (ll)dsub((double)i, dmul(1.3, (double)w)); if (cr < 0) cr = 0;
    } else {
      cl = (ll)dadd((double)i, dmul(0.3, (double)w));
      cr = (ll)dadd((double)i, dmul(0.75, (double)w));
    }
    ll s = i - (ll)(w / 2); if (s < 0) s = 0;
    bool valid = !(cl == cr || (T - cl) < (ll)w || (s + (ll)w) > T);
    double corrd; ll ipos; double peakd;
    if (!valid) {
      corrd = -1.0; ipos = i; peakd = 0.0;
      // keep prefetch rolling even on invalid steps (i moves by +-w)
      ll pb = dir ? (i + (ll)(w >> 2) - 8) : (i - 3 * (ll)w - 16);
      bool ok = (pb >= 0) && (pb + PFW <= T);
      if (ok) {
        #pragma unroll
        for (int j = 0; j < PFN; ++j) pstg[j] = snd[pb + (ll)(j * 64) + lane];
        pf_base = pb;
      }
      pf_ok = ok;
    } else {
      ll L = cr + (ll)w; if (L > T) L = T; L -= cl;
      int ncand = (int)(L - (ll)w + 1);           // 1..121
      ll lo = (s < cl) ? s : cl;
      ll hiA = s + (ll)w;
      ll hiB = cl + L;
      ll hi = (hiA > hiB) ? hiA : hiB;
      int len = (int)(hi - lo);                   // <= 599
      float* lxb = bsel ? lxB : lxA;
      bool covered = pf_ok && (lo >= pf_base) && (hi <= pf_base + PFW);
      if (covered) {
        // prefetched last step: registers -> LDS, zero global wait
        #pragma unroll
        for (int j = 0; j < PFN; ++j) {
          int k = (int)((pf_base + (ll)(j * 64) + lane) - lo);
          if (k >= 0 && k < len) lxb[k] = fsub(pstg[j], mean);
        }
      } else {
        float stg[10];
        #pragma unroll
        for (int j = 0; j < 5; ++j) {
          ll a = lo + (ll)(j * 64) + lane;
          if (a > T - 1) a = T - 1;
          stg[j] = snd[a];
        }
        bool big = (len > 320);
        if (big) {
          #pragma unroll
          for (int j = 5; j < 10; ++j) {
            ll a = lo + (ll)(j * 64) + lane;
            if (a > T - 1) a = T - 1;
            stg[j] = snd[a];
          }
        }
        #pragma unroll
        for (int j = 0; j < 5; ++j) {
          int k = j * 64 + lane;
          if (k < len) lxb[k] = fsub(stg[j], mean);
        }
        if (big) {
          #pragma unroll
          for (int j = 5; j < 10; ++j) {
            int k = j * 64 + lane;
            if (k < len) lxb[k] = fsub(stg[j], mean);
          }
        }
      }
      // issue NEXT step's speculative prefetch (latency hides under compute)
      {
        ll pb = dir ? (i + (ll)(w >> 2) - 8) : (i - 3 * (ll)w - 16);
        bool ok = (pb >= 0) && (pb + PFW <= T);
        if (ok) {
          #pragma unroll
          for (int j = 0; j < PFN; ++j) pstg[j] = snd[pb + (ll)(j * 64) + lane];
          pf_base = pb;
        }
        pf_ok = ok;
      }
      WBAR();  // LDS writes visible; vmcnt (prefetch) NOT drained
      int toff = (int)(s - lo);
      int coff = (int)(cl - lo);
      // fused template norm + slot-0 candidate norm (independent chains)
      int r0 = lane;
      int rc0 = (r0 < ncand) ? r0 : (ncand - 1);
      float pk0 = 0.0f;
      float tsq, csq0;
      pw2_sq(lxb, toff, coff + rc0, w, tsq, csq0, pk0);
      float tn = __fsqrt_rn(tsq);
      float tdiv = (float)fmax((double)tn, 1e-12);
      float rt = __fdiv_rn(1.0f, tdiv);
      float nr0 = __fsqrt_rn(csq0);
      float divr0 = fmaxf(nr0, (float)1e-12);
      float rr0 = __fdiv_rn(1.0f, divr0);
      // slot-1 candidate norm (independent of template; before the barrier)
      float pk1 = 0.0f, divr1 = 1.0f, rr1 = 1.0f;
      int rc1 = 0;
      bool has1 = (ncand > 64);
      if (has1) {
        int r1 = lane + 64;
        rc1 = (r1 < ncand) ? r1 : (ncand - 1);
        float nr1 = __fsqrt_rn(pw1_sq(lxb, coff + rc1, w, pk1));
        divr1 = fmaxf(nr1, (float)1e-12);
        rr1 = __fdiv_rn(1.0f, divr1);
      }
      // normalized template -> LDS (Markstein division == __fdiv_rn bitwise)
      for (int k = lane; k < w; k += 64) ltm[k] = div_exact(lxb[toff + k], tdiv, rt);
      WBAR();
      // dots
      float co0 = dot_lds(lxb, coff + rc0, divr0, rr0, ltm, w);
      float co1 = -INFINITY;
      if (has1) {
        co1 = dot_lds(lxb, coff + rc1, divr1, rr1, ltm, w);
        if (lane + 64 >= ncand) co1 = -INFINITY;
      }
      // fold slots (prefer higher corr; ties -> lower index)
      float bv = (r0 < ncand) ? co0 : -INFINITY;
      int bi = (r0 < ncand) ? r0 : 0x7FFFFFFF;
      {
        int i1 = lane + 64;
        if (co1 > bv || (co1 == bv && i1 < bi)) { bv = co1; bi = i1; }
      }
      // butterfly argmax (first-occurrence tie-break, matches serial scan)
      for (int off = 32; off > 0; off >>= 1) {
        float ov = __shfl_xor(bv, off);
        int oi = __shfl_xor(bi, off);
        if (ov > bv || (ov == bv && oi < bi)) { bv = ov; bi = oi; }
      }
      corrd = (double)bv;
      ipos = i + ((ll)bi + cl) - s;
      {
        int ol = bi & 63;
        float p0f = __shfl(pk0, ol);
        float p1f = __shfl(pk1, ol);
        peakd = (double)((bi < 64) ? p0f : p1f);
      }
      bsel ^= 1;
    }
    // decision (all lanes redundantly; lane 0 writes)
    ll inew;
    if (dir == 0) {
      inew = (corrd == -1.0) ? (i - (ll)w) : ipos;
      if (inew < left) {
        if (corrd > 0.7 && peakd > dmul(0.023333, gpeak) &&
            (dsub((double)inew, added_right) > dmul(0.8, (double)w))) {
          if (cnt < MAXCHAIN) { if (lane == 0) mybuf[cnt] = (int)inew; ++cnt; }
        }
        stop = true;
      } else {
        if (corrd > 0.3 && (peakd == 0.0 || peakd > dmul(0.01, gpeak))) {
          if (dsub((double)inew, added_right) > dmul(0.8, (double)w)) {
            if (cnt < MAXCHAIN) { if (lane == 0) mybuf[cnt] = (int)inew; ++cnt; }
          }
        }
        i = inew;
      }
    } else {
      inew = (corrd == -1.0) ? (i + (ll)w) : ipos;
      if (inew >= right) {
        if (corrd > 0.7 && peakd > dmul(0.023333, gpeak)) {
          if (cnt < MAXCHAIN) { if (lane == 0) mybuf[cnt] = (int)inew; ++cnt; }
        }
        stop = true;
      } else {
        if (corrd > 0.3 && (peakd == 0.0 || peakd > dmul(0.01, gpeak))) {
          if (cnt < MAXCHAIN) { if (lane == 0) mybuf[cnt] = (int)inew; ++cnt; }
          added_right = (double)inew;
        }
        i = inew;
      }
    }
  }
  if (lane == 0) c->chain_cnt[chain] = cnt;
}

// fused: per-chain offset computation + gather (block 0 also writes n_peaks)
__global__ void k_gather(char* wsb, ll T) {
  Ctrl* c = (Ctrl*)wsb;
  int chain = blockIdx.x;
  int cnt = c->chain_cnt[chain];
  int off = 0;
  for (int ch = 0; ch < chain; ++ch) off += c->chain_cnt[ch];
  const int* mybuf = ((const int*)(wsb + CHAINS_OFF)) + (ll)chain * MAXCHAIN;
  int* peaks = (int*)(wsb + PEAKS_OFF);
  int dir = chain & 1;
  for (int k = threadIdx.x; k < cnt; k += blockDim.x) {
    if (off + k < MAXP) {
      int v = dir ? mybuf[k] : mybuf[cnt - 1 - k];  // left chains stored descending
      if (v < 0) v = 0;
      if ((ll)v > T - 1) v = (int)(T - 1);
      peaks[off + k] = v;
    }
  }
  if (chain == 0 && threadIdx.x == 0) {
    int tot = 0;
    for (int ch = 0; ch < 128; ++ch) tot += c->chain_cnt[ch];
    c->n_peaks = (tot > MAXP) ? MAXP : tot;
  }
}

#define PSLDS 3584
#define PPS 2048

__global__ __launch_bounds__(64) void k_psola(const float* __restrict__ pitch, ll T, ll S,
                                              double ratio, char* wsb,
                                              const float* ps, const float* pr) {
  Ctrl* c = (Ctrl*)wsb;
  int r = blockIdx.x;
  if (r >= c->nregions) return;
  const int* peaks = (const int*)(wsb + PEAKS_OFF);
  int np = c->n_peaks;
  int tid = threadIdx.x;
  ll left = (ll)c->region_start[r], right = (ll)c->region_end[r];

  __shared__ int lp[PSLDS];
  __shared__ float lpitch[PPS];
  __shared__ int sh_g0, sh_g1, sh_use;

  // stage pitch frames for f0 reads at lv in [left, right)
  ll tA = left - 600; if (tA < 0) tA = 0;
  ll tB = right + 600; if (tB > T - 1) tB = T - 1;
  ll p0l = frame_lo(tA, S, ratio);
  ll p1l = frame_lo(tB, S, ratio) + 1; if (p1l > S - 1) p1l = S - 1;
  int p0 = (int)p0l, p1 = (int)p1l;
  int span = p1 - p0 + 1;
  if (span <= PPS) {
    for (int k = tid; k < span; k += 64) lpitch[k] = pitch[p0 + k];
  } else { p0 = 0; p1 = -1; }

  if (np > 0) {
    if (tid == 0) {
      int lo = 0, hi = np;
      ll tgt = left - 512;
      while (lo < hi) { int m = (lo + hi) >> 1; if ((ll)peaks[m] < tgt) lo = m + 1; else hi = m; }
      int a = lo;
      lo = 0; hi = np; tgt = right + 512;
      while (lo < hi) { int m = (lo + hi) >> 1; if ((ll)peaks[m] < tgt) lo = m + 1; else hi = m; }
      int b = lo;
      a -= 4; if (a < 0) a = 0;
      b += 4; if (b > np) b = np;
      sh_g0 = a; sh_g1 = b; sh_use = (b - a <= PSLDS) ? 1 : 0;
    }
    __syncthreads();
    if (sh_use) {
      for (int k = sh_g0 + tid; k < sh_g1; k += 64) lp[k - sh_g0] = peaks[k];
    }
  }
  __syncthreads();
  if (tid != 0) return;

  int g0 = (np > 0 && sh_use) ? sh_g0 : 0;
  const int* pk = (np > 0 && sh_use) ? lp : peaks;

  int slab = c->slab;
  int4* myops = ((int4*)(wsb + OPS_OFF)) + (ll)r * slab;
  int cnt = 0;
  ll prev_end = (r == 0) ? 0 : (ll)c->region_end[r - 1];
  ll lv = left, rv = right;
  double max_w = c->max_w;
  float md32 = c->md32, psv = ps[0], prv = pr[0];

  ll gapn = lv - prev_end;
  if (gapn > 0) {
    if (cnt < slab) myops[cnt] = make_int4((int)prev_end, (int)prev_end, (int)gapn, (int)gapn);
    ++cnt;
  }
  if (np > 0) {
    int j;
    {
      int loJ = 0, hiJ = np;
      while (loJ < hiJ) {
        int mid = (loJ + hiJ) >> 1;
        if ((ll)peaks[mid] < lv) loJ = mid + 1; else hiJ = mid;
      }
      j = loJ;
    }
    for (long itc = 0; itc < 2000000 && lv < rv; ++itc) {
      float f = f0_lds(lpitch, p0, p1, pitch, lv, S, ratio);
      float u = fmul(f, psv);
      float fs = (!(u > 0.0f)) ? 0.0f : fadd(md32, fmul(fsub(u, md32), prv));
      int period = (int)(16000.0 / fmax((double)fs, 60.0));
      int lw = period / 2, rw = period / 2;
      while (j < np && (ll)pk[j - g0] < lv) ++j;
      ll dl = (j > 0) ? (lv - (ll)pk[j - 1 - g0]) : LLONG_MAX;
      ll dr = (j < np) ? ((ll)pk[j - g0] - lv) : LLONG_MAX;
      int p;
      if (dl <= dr) {
        int q = j - 1; int v = pk[q - g0];
        while (q > 0 && pk[q - 1 - g0] == v) --q;
        p = q;
      } else {
        int q = j; int v = pk[q - g0];
        while (q > 0 && pk[q - 1 - g0] == v) --q;
        p = q;
      }
      if (p > 0) {
        ll g = (ll)pk[p - g0] - (ll)pk[p - 1 - g0];
        if ((double)g <= max_w && g < (ll)lw) lw = (int)g;
      }
      if (p < np - 1) {
        ll g = (ll)pk[p + 1 - g0] - (ll)pk[p - g0];
        if ((double)g <= max_w && g < (ll)rw) rw = (int)g;
      }
      ll li = (ll)pk[p - g0] - (ll)lw; if (li < 0) li = 0;
      ll ri = (ll)pk[p - g0] + (ll)rw;
      ll ival = (ri - li) / 2;
      if (ival <= 0) { lv += (period > 1 ? (ll)period : 1); continue; }
      ll a = lv - ival, b = lv + ival;
      ll st = (a < 0) ? ((a + T > 0) ? a + T : 0) : ((a < T) ? a : T);
      ll sp = (b < 0) ? ((b + T > 0) ? b + T : 0) : ((b < T) ? b : T);
      ll dst_len = sp - st; if (dst_len < 0) dst_len = 0;
      ll se = li + 2 * ival; if (se > T) se = T;
      ll src_len = se - li; if (src_len < 0) src_len = 0;
      ll seglen = dst_len < src_len ? dst_len : src_len;
      if (seglen > 0) {
        if (cnt < slab) myops[cnt] = make_int4((int)st, (int)li, (int)seglen, (int)(2 * ival));
        ++cnt;
      }
      lv += 2 * ival;
    }
  }
  c->region_ops[r] = (cnt > slab) ? slab : cnt;
}

__global__ void k_scatter(const float* __restrict__ snd, char* wsb, float* out, ll T) {
  Ctrl* c = (Ctrl*)wsb;
  float mean = c->mean32;
  int nr = c->nregions; if (nr > MAXR) nr = MAXR;
  int slab = c->slab;
  const int4* ops = (const int4*)(wsb + OPS_OFF);
  ll total = (ll)nr * slab;
  for (ll idx = blockIdx.x; idx < total; idx += gridDim.x) {
    int r = (int)(idx / slab);
    int o = (int)(idx - (ll)r * slab);
    if (o >= c->region_ops[r]) continue;
    int4 op = ops[(ll)r * slab + o];
    ll dst = (ll)op.x, src = (ll)op.y; int n = op.z, m = op.w;
    for (int k = threadIdx.x; k < n; k += blockDim.x) {
      double ang = dmul(TWOPI, (double)k) / (double)m;
      float w32 = (float)dsub(0.5, dmul(0.5, cos(ang)));
      float val = fmul(w32, xval(snd, mean, src + k));
      atomicAdd(&out[dst + k], val);
    }
  }
}

__global__ void k_final(const float* __restrict__ snd, char* wsb, float* out, ll T) {
  Ctrl* c = (Ctrl*)wsb;
  float mean = c->mean32;
  ll tail = c->tail;
  ll stride = (ll)gridDim.x * blockDim.x;
  for (ll t = (ll)blockIdx.x * blockDim.x + threadIdx.x; t < T; t += stride)
    if (t >= tail) out[t] = xval(snd, mean, t);
}

extern "C" void kernel_launch(void* const* d_in, const int* in_sizes, int n_in,
                              void* d_out, int out_size, void* d_ws, size_t ws_size,
                              hipStream_t stream) {
  ll T = (ll)in_sizes[0];
  ll S = (ll)in_sizes[1];
  const float* snd = (const float*)d_in[0];
  const float* pitch = (const float*)d_in[1];
  const float* ps = (const float*)d_in[2];
  const float* pr = (const float*)d_in[3];
  float* out = (float*)d_out;
  char* wsb = (char*)d_ws;
  double ratio = (double)S / (double)T;

  size_t f0_need = F0_OFF + (size_t)T * 4;
  int cached = (ws_size >= f0_need) ? 1 : 0;
  unsigned* f0bits = (unsigned*)(wsb + F0_OFF);

  k_init_sum<<<1024, 256, 0, stream>>>(snd, T, wsb);
  k_sum_final<<<1, 256, 0, stream>>>(wsb, T, 1024);
  k_scan<<<2048, 256, 0, stream>>>(snd, pitch, T, S, ratio, wsb, f0bits, cached);
  k_prep<<<1, 1, 0, stream>>>(wsb, ps);
  for (int pass = 0; pass < 4; ++pass) {
    k_hist<<<2048, 256, 0, stream>>>(pitch, T, S, ratio, wsb, f0bits, cached);
    k_sel<<<1, 1, 0, stream>>>(wsb, ps, pr);
  }
  k_walks<<<128, 64, 0, stream>>>(snd, pitch, T, S, ratio, wsb);
  k_gather<<<128, 64, 0, stream>>>(wsb, T);
  k_psola<<<64, 64, 0, stream>>>(pitch, T, S, ratio, wsb, ps, pr);
  hipMemsetAsync(d_out, 0, (size_t)out_size * sizeof(float), stream);
  k_scatter<<<8192, 128, 0, stream>>>(snd, wsb, out, T);
  k_final<<<2048, 256, 0, stream>>>(snd, wsb, out, T);
}